// Round 8
// baseline (547.802 us; speedup 1.0000x reference)
//
#include <hip/hip_runtime.h>
#include <hip/hip_cooperative_groups.h>

// MS-SSIM, 5 levels, 16x3x512x512 fp32, scalar fp32 out.
//
// R8: cooperative mega-kernel (R7) hardened:
//  - grid sized from hipOccupancyMaxActiveBlocksPerMultiprocessor (the
//    runtime's own capacity number), clamped to <=8 blocks/CU x 256 CUs;
//  - hipLaunchCooperativeKernel return code checked; on failure fall back
//    to the R6 multi-dispatch path (same ssim_tile device code) so the
//    answer is always correct;
//  - __launch_bounds__(256,4): compiler keeps natural ~52-60 VGPR (R5/R6's
//    forced-32 caused spill FETCH/WRITE traffic), LDS 19.5KB -> up to 8
//    blocks/CU.
// Kernel internals = R6 (verified absmax 0): s/d channel reduction, fp16
// LDS h-channel tiles, rolling v-pass, fused 2x2 avg-pool for next level.

#define NSLOT 32

namespace cg = cooperative_groups;

typedef float v4  __attribute__((ext_vector_type(4)));
typedef float v2f __attribute__((ext_vector_type(2)));
typedef _Float16 h4 __attribute__((ext_vector_type(4)));

__device__ __forceinline__ float frcp(float x) { return __builtin_amdgcn_rcpf(x); }

template<int TROWS>
__device__ __forceinline__ void ssim_tile(
    const float* __restrict__ img1, const float* __restrict__ img2,
    float* __restrict__ ds1, float* __restrict__ ds2,
    int H, int do_ds, float* __restrict__ acc,
    int nc, int tx0, int ty0, h4* hb, float* red, int tid)
{
    constexpr int HR    = TROWS + 10;        // h-rows per tile
    constexpr int OPT   = TROWS * 32 / 256;  // output rows per thread
    constexpr int PITCH = 33;                // pixels per LDS row (32+1 pad)

    const float GW[11] = {0.00102840f, 0.00759877f, 0.03600070f, 0.10936069f,
                          0.21300636f, 0.26601172f, 0.21300636f, 0.10936069f,
                          0.03600070f, 0.00759877f, 0.00102840f};
    const float C1 = 1e-4f, C2 = 9e-4f;

    const int outHW = H - 10;
    const float* p1 = img1 + (size_t)nc * H * H;
    const float* p2 = img2 + (size_t)nc * H * H;

    // ---- fused 2x2 avg-pool of the block's core region (independent work)
    if (do_ds) {
        const int H2 = H >> 1;
        #pragma unroll
        for (int t = tid; t < 16 * (TROWS / 2); t += 256) {
            int r = t >> 4, cdd = t & 15;
            int iy = ty0 + 2 * r, ix = tx0 + 2 * cdd;
            if (iy + 1 < H) {
                v2f a0 = *(const v2f*)(p1 + (size_t)iy * H + ix);
                v2f a1 = *(const v2f*)(p1 + (size_t)(iy + 1) * H + ix);
                v2f b0 = *(const v2f*)(p2 + (size_t)iy * H + ix);
                v2f b1 = *(const v2f*)(p2 + (size_t)(iy + 1) * H + ix);
                size_t o = (size_t)nc * H2 * H2
                         + (size_t)((ty0 >> 1) + r) * H2 + ((tx0 >> 1) + cdd);
                ds1[o] = 0.25f * ((a0.x + a0.y) + (a1.x + a1.y));
                ds2[o] = 0.25f * ((b0.x + b0.y) + (b1.x + b1.y));
            }
        }
    }

    // ---- horizontal pass: HR rows x 8 col-groups (4 cols each)
    for (int task = tid; task < HR * 8; task += 256) {
        const int r  = task >> 3, cg_ = task & 7;
        const int gr = ty0 + r;
        const int c0 = tx0 + cg_ * 4;
        v4 hs = 0.f, hd = 0.f, hss = 0.f, hdd = 0.f;
        if (gr < H) {
            float s[16], d[16];
            if (c0 + 16 <= H) {
                const float* pa = p1 + (size_t)gr * H + c0;
                const float* pb = p2 + (size_t)gr * H + c0;
                #pragma unroll
                for (int q = 0; q < 4; ++q) {
                    v4 va = *(const v4*)(pa + 4 * q);
                    v4 vb = *(const v4*)(pb + 4 * q);
                    v4 sv = va + vb, dv = va - vb;
                    s[4*q+0] = sv.x; s[4*q+1] = sv.y; s[4*q+2] = sv.z; s[4*q+3] = sv.w;
                    d[4*q+0] = dv.x; d[4*q+1] = dv.y; d[4*q+2] = dv.z; d[4*q+3] = dv.w;
                }
            } else {
                #pragma unroll
                for (int q = 0; q < 16; ++q) {
                    int cc = c0 + q;
                    float a = (cc < H) ? p1[(size_t)gr * H + cc] : 0.f;
                    float b = (cc < H) ? p2[(size_t)gr * H + cc] : 0.f;
                    s[q] = a + b; d[q] = a - b;
                }
            }
            #pragma unroll
            for (int j = 0; j < 11; ++j) {
                float w = GW[j];
                v4 sv = {s[j], s[j+1], s[j+2], s[j+3]};
                v4 dv = {d[j], d[j+1], d[j+2], d[j+3]};
                v4 ws_ = w * sv, wd = w * dv;
                hs += ws_; hd += wd; hss += ws_ * sv; hdd += wd * dv;
            }
        }
        h4* row = &hb[r * PITCH + cg_ * 4];
        row[0] = (h4){(_Float16)hs.x, (_Float16)hd.x, (_Float16)hss.x, (_Float16)hdd.x};
        row[1] = (h4){(_Float16)hs.y, (_Float16)hd.y, (_Float16)hss.y, (_Float16)hdd.y};
        row[2] = (h4){(_Float16)hs.z, (_Float16)hd.z, (_Float16)hss.z, (_Float16)hdd.z};
        row[3] = (h4){(_Float16)hs.w, (_Float16)hd.w, (_Float16)hss.w, (_Float16)hdd.w};
    }
    __syncthreads();

    // ---- vertical pass + ssim/cs: thread = 1 column x OPT rows (rolling)
    const int col  = tid & 31;
    const int row0 = (tid >> 5) * OPT;
    const float colm = (tx0 + col < outHW) ? 1.f : 0.f;
    v4 A[OPT];
    #pragma unroll
    for (int k = 0; k < OPT; ++k) A[k] = 0.f;

    #pragma unroll
    for (int r = 0; r < OPT + 10; ++r) {
        h4 h = hb[(row0 + r) * PITCH + col];
        v4 f = {(float)h.x, (float)h.y, (float)h.z, (float)h.w};
        #pragma unroll
        for (int k = 0; k < OPT; ++k) {
            const int j = r - k;
            if (j >= 0 && j < 11) A[k] += GW[j] * f;
        }
    }

    float ssim_t = 0.f, cs_t = 0.f;
    #pragma unroll
    for (int k = 0; k < OPT; ++k) {
        float mask = colm * ((ty0 + row0 + k < outHW) ? 1.f : 0.f);
        float mu_s = A[k].x, mu_d = A[k].y;
        float P = mu_s * mu_s, Q = mu_d * mu_d;
        float U = A[k].z - P, V = A[k].w - Q;
        float v1 = 0.5f * (U - V) + C2;
        float v2 = 0.5f * (U + V) + C2;
        float n1 = 0.5f * (P - Q) + C1;
        float d1 = 0.5f * (P + Q) + C1;
        float csv = v1 * frcp(v2);
        float ssv = n1 * csv * frcp(d1);
        cs_t   += mask * csv;
        ssim_t += mask * ssv;
    }

    // ---- block reduction + spread atomics
    #pragma unroll
    for (int off = 32; off > 0; off >>= 1) {
        ssim_t += __shfl_down(ssim_t, off);
        cs_t   += __shfl_down(cs_t, off);
    }
    int wave = tid >> 6, lane = tid & 63;
    if (lane == 0) { red[wave] = ssim_t; red[4 + wave] = cs_t; }
    __syncthreads();
    if (tid == 0) {
        float s = red[0] + red[1] + red[2] + red[3];
        float c2s = red[4] + red[5] + red[6] + red[7];
        int slot = (tx0 + ty0 * 5 + nc * 11) & (NSLOT - 1);
        atomicAdd(&acc[slot], s);
        atomicAdd(&acc[NSLOT + slot], c2s);
    }
}

__device__ __forceinline__ void finalize_body(const float* __restrict__ acc,
                                              float* __restrict__ out)
{
    const float w[5] = {0.0448f, 0.2856f, 0.3001f, 0.2363f, 0.1333f};
    float ms[5], mc[5];
    for (int l = 0; l < 5; ++l) {
        float s = 0.f, c = 0.f;
        for (int k = 0; k < NSLOT; ++k) {
            s += acc[2 * NSLOT * l + k];
            c += acc[2 * NSLOT * l + NSLOT + k];
        }
        int oh = (512 >> l) - 10;
        float cnt = 48.f * (float)oh * (float)oh;
        ms[l] = (s / cnt + 1.f) * 0.5f;
        mc[l] = (c / cnt + 1.f) * 0.5f;
    }
    float p2 = powf(ms[4], w[4]);
    float r = 1.f;
    for (int i = 0; i < 4; ++i) r *= powf(mc[i], w[i]) * p2;
    out[0] = r;
}

// ---------------- cooperative mega-kernel ----------------

__global__ __launch_bounds__(256, 4) void ssim_all_kernel(
    const float* __restrict__ img1, const float* __restrict__ img2,
    float* __restrict__ ws, float* __restrict__ out)
{
    __shared__ h4 hb[74 * 33];
    __shared__ float red[8];

    const int tid = threadIdx.x;
    const int bid = blockIdx.x;
    const int nb  = gridDim.x;
    cg::grid_group grid = cg::this_grid();

    float* acc = ws;
    float* l1a = ws + 512;      float* l1b = ws + 3146240;
    float* l2a = ws + 6291968;  float* l2b = ws + 7078400;
    float* l3a = ws + 7864832;  float* l3b = ws + 8061440;
    float* l4a = ws + 8258048;  float* l4b = ws + 8307200;

    if (bid == 0)
        for (int i = tid; i < 2 * NSLOT * 5; i += 256) acc[i] = 0.f;
    grid.sync();

    for (int t = bid; t < 6144; t += nb) {            // L0: H=512 T=64 16x8x48
        int nc = t >> 7, k = t & 127;
        ssim_tile<64>(img1, img2, l1a, l1b, 512, 1, acc,
                      nc, (k & 15) * 32, (k >> 4) * 64, hb, red, tid);
    }
    grid.sync();

    for (int t = bid; t < 1536; t += nb) {            // L1: H=256 T=64 8x4x48
        int nc = t >> 5, k = t & 31;
        ssim_tile<64>(l1a, l1b, l2a, l2b, 256, 1, acc + 64,
                      nc, (k & 7) * 32, (k >> 3) * 64, hb, red, tid);
    }
    grid.sync();

    for (int t = bid; t < 768; t += nb) {             // L2: H=128 T=32 4x4x48
        int nc = t >> 4, k = t & 15;
        ssim_tile<32>(l2a, l2b, l3a, l3b, 128, 1, acc + 128,
                      nc, (k & 3) * 32, (k >> 2) * 32, hb, red, tid);
    }
    grid.sync();

    for (int t = bid; t < 384; t += nb) {             // L3: H=64 T=16 2x4x48
        int nc = t >> 3, k = t & 7;
        ssim_tile<16>(l3a, l3b, l4a, l4b, 64, 1, acc + 192,
                      nc, (k & 1) * 32, (k >> 1) * 16, hb, red, tid);
    }
    grid.sync();

    for (int t = bid; t < 96; t += nb) {              // L4: H=32 T=16 1x2x48
        int nc = t >> 1, k = t & 1;
        ssim_tile<16>(l4a, l4b, nullptr, nullptr, 32, 0, acc + 256,
                      nc, 0, k * 16, hb, red, tid);
    }
    grid.sync();

    if (bid == 0 && tid == 0) finalize_body(acc, out);
}

// ---------------- fallback multi-dispatch path ----------------

template<int TROWS>
__global__ __launch_bounds__(256, 4) void ssim_level_kernel(
    const float* __restrict__ img1, const float* __restrict__ img2,
    float* __restrict__ ds1, float* __restrict__ ds2,
    int H, int do_ds, float* __restrict__ acc)
{
    __shared__ h4 hb[(TROWS + 10) * 33];
    __shared__ float red[8];
    ssim_tile<TROWS>(img1, img2, ds1, ds2, H, do_ds, acc,
                     blockIdx.z, blockIdx.x * 32, blockIdx.y * TROWS,
                     hb, red, threadIdx.x);
}

__global__ void finalize_kernel(const float* __restrict__ acc, float* __restrict__ out)
{
    if (threadIdx.x == 0 && blockIdx.x == 0) finalize_body(acc, out);
}

extern "C" void kernel_launch(void* const* d_in, const int* in_sizes, int n_in,
                              void* d_out, int out_size, void* d_ws, size_t ws_size,
                              hipStream_t stream)
{
    const float* img1 = (const float*)d_in[0];
    const float* img2 = (const float*)d_in[1];
    float* out = (float*)d_out;
    float* ws  = (float*)d_ws;

    // ---- try the cooperative mega-kernel, sized by the runtime's capacity
    int bpc = 0;
    hipError_t qerr = hipOccupancyMaxActiveBlocksPerMultiprocessor(
        &bpc, ssim_all_kernel, 256, 0);
    bool ok = false;
    if (qerr == hipSuccess && bpc > 0) {
        if (bpc > 8) bpc = 8;
        int nblocks = bpc * 256;                 // 256 CUs on MI355X
        if (nblocks > 6144) nblocks = 6144;
        void* args[] = {(void*)&img1, (void*)&img2, (void*)&ws, (void*)&out};
        hipError_t lerr = hipLaunchCooperativeKernel(
            ssim_all_kernel, dim3(nblocks), dim3(256), args, 0, stream);
        ok = (lerr == hipSuccess);
    }
    if (ok) return;

    // ---- fallback: R6-style multi-dispatch (always correct)
    float* acc = ws;
    float* l1a = ws + 512;      float* l1b = ws + 3146240;
    float* l2a = ws + 6291968;  float* l2b = ws + 7078400;
    float* l3a = ws + 7864832;  float* l3b = ws + 8061440;
    float* l4a = ws + 8258048;  float* l4b = ws + 8307200;

    hipMemsetAsync(acc, 0, 5 * 2 * NSLOT * sizeof(float), stream);

    ssim_level_kernel<64><<<dim3(16, 8, 48), 256, 0, stream>>>(
        img1, img2, l1a, l1b, 512, 1, acc);
    ssim_level_kernel<64><<<dim3(8, 4, 48), 256, 0, stream>>>(
        l1a, l1b, l2a, l2b, 256, 1, acc + 64);
    ssim_level_kernel<32><<<dim3(4, 4, 48), 256, 0, stream>>>(
        l2a, l2b, l3a, l3b, 128, 1, acc + 128);
    ssim_level_kernel<16><<<dim3(2, 4, 48), 256, 0, stream>>>(
        l3a, l3b, l4a, l4b, 64, 1, acc + 192);
    ssim_level_kernel<16><<<dim3(1, 2, 48), 256, 0, stream>>>(
        l4a, l4b, nullptr, nullptr, 32, 0, acc + 256);

    finalize_kernel<<<1, 64, 0, stream>>>(acc, out);
}

// Round 9
// 339.839 us; speedup vs baseline: 1.6119x; 1.6119x over previous
//
#include <hip/hip_runtime.h>
#include <hip/hip_cooperative_groups.h>

// MS-SSIM, 5 levels, 16x3x512x512 fp32, scalar fp32 out.
//
// R9: cooperative mega-kernel with a hand-rolled inter-level barrier.
// R8 showed cg::grid.sync() costs ~100us each (single-counter arrivals +
// s_sleep backoff) -> 6 syncs ~ 650us of stall (VALUBusy 7%). Replacement:
// monotonic counter barrier, arrivals spread over 32 cache lines, block 0
// sums and publishes a generation word (agent-scope release); others spin
// relaxed + s_sleep. __threadfence() on both sides gives the cross-XCD
// release/acquire for the downsample buffers. Acc + barrier state zeroed by
// a hipMemsetAsync node preceding the cooperative node (init barrier gone;
// 5 barriers remain). Kernel internals = R6/R8 verified ssim_tile.
// Fallback multi-dispatch path kept (cooperative launch rc checked).

#define NSLOT 32

namespace cg = cooperative_groups;

typedef float v4  __attribute__((ext_vector_type(4)));
typedef float v2f __attribute__((ext_vector_type(2)));
typedef _Float16 h4 __attribute__((ext_vector_type(4)));

__device__ __forceinline__ float frcp(float x) { return __builtin_amdgcn_rcpf(x); }

// ---- grid barrier: monotonic, 32 spread arrival lines, gen publish
__device__ __forceinline__ void grid_bar(unsigned* cnt, unsigned* gen,
                                         unsigned nb, unsigned round,
                                         int tid, int bid)
{
    __syncthreads();
    if (tid == 0) {
        __threadfence();                       // release prior writes
        atomicAdd(&cnt[(bid & 31) * 16], 1u);  // arrival (own cache line)
        if (bid == 0) {
            const unsigned target = nb * round;
            for (;;) {
                unsigned s = 0;
                #pragma unroll
                for (int i = 0; i < 32; ++i)
                    s += __hip_atomic_load(&cnt[i * 16], __ATOMIC_RELAXED,
                                           __HIP_MEMORY_SCOPE_AGENT);
                if (s >= target) break;
                __builtin_amdgcn_s_sleep(2);
            }
            __hip_atomic_store(gen, round, __ATOMIC_RELEASE,
                               __HIP_MEMORY_SCOPE_AGENT);
        } else {
            while (__hip_atomic_load(gen, __ATOMIC_RELAXED,
                                     __HIP_MEMORY_SCOPE_AGENT) < round)
                __builtin_amdgcn_s_sleep(2);
        }
        __threadfence();                       // acquire others' writes
    }
    __syncthreads();
}

template<int TROWS>
__device__ __forceinline__ void ssim_tile(
    const float* __restrict__ img1, const float* __restrict__ img2,
    float* __restrict__ ds1, float* __restrict__ ds2,
    int H, int do_ds, float* __restrict__ acc,
    int nc, int tx0, int ty0, h4* hb, float* red, int tid)
{
    constexpr int HR    = TROWS + 10;        // h-rows per tile
    constexpr int OPT   = TROWS * 32 / 256;  // output rows per thread
    constexpr int PITCH = 33;                // pixels per LDS row (32+1 pad)

    const float GW[11] = {0.00102840f, 0.00759877f, 0.03600070f, 0.10936069f,
                          0.21300636f, 0.26601172f, 0.21300636f, 0.10936069f,
                          0.03600070f, 0.00759877f, 0.00102840f};
    const float C1 = 1e-4f, C2 = 9e-4f;

    const int outHW = H - 10;
    const float* p1 = img1 + (size_t)nc * H * H;
    const float* p2 = img2 + (size_t)nc * H * H;

    // ---- fused 2x2 avg-pool of the block's core region (independent work)
    if (do_ds) {
        const int H2 = H >> 1;
        #pragma unroll
        for (int t = tid; t < 16 * (TROWS / 2); t += 256) {
            int r = t >> 4, cdd = t & 15;
            int iy = ty0 + 2 * r, ix = tx0 + 2 * cdd;
            if (iy + 1 < H) {
                v2f a0 = *(const v2f*)(p1 + (size_t)iy * H + ix);
                v2f a1 = *(const v2f*)(p1 + (size_t)(iy + 1) * H + ix);
                v2f b0 = *(const v2f*)(p2 + (size_t)iy * H + ix);
                v2f b1 = *(const v2f*)(p2 + (size_t)(iy + 1) * H + ix);
                size_t o = (size_t)nc * H2 * H2
                         + (size_t)((ty0 >> 1) + r) * H2 + ((tx0 >> 1) + cdd);
                ds1[o] = 0.25f * ((a0.x + a0.y) + (a1.x + a1.y));
                ds2[o] = 0.25f * ((b0.x + b0.y) + (b1.x + b1.y));
            }
        }
    }

    // ---- horizontal pass: HR rows x 8 col-groups (4 cols each)
    for (int task = tid; task < HR * 8; task += 256) {
        const int r  = task >> 3, cg_ = task & 7;
        const int gr = ty0 + r;
        const int c0 = tx0 + cg_ * 4;
        v4 hs = 0.f, hd = 0.f, hss = 0.f, hdd = 0.f;
        if (gr < H) {
            float s[16], d[16];
            if (c0 + 16 <= H) {
                const float* pa = p1 + (size_t)gr * H + c0;
                const float* pb = p2 + (size_t)gr * H + c0;
                #pragma unroll
                for (int q = 0; q < 4; ++q) {
                    v4 va = *(const v4*)(pa + 4 * q);
                    v4 vb = *(const v4*)(pb + 4 * q);
                    v4 sv = va + vb, dv = va - vb;
                    s[4*q+0] = sv.x; s[4*q+1] = sv.y; s[4*q+2] = sv.z; s[4*q+3] = sv.w;
                    d[4*q+0] = dv.x; d[4*q+1] = dv.y; d[4*q+2] = dv.z; d[4*q+3] = dv.w;
                }
            } else {
                #pragma unroll
                for (int q = 0; q < 16; ++q) {
                    int cc = c0 + q;
                    float a = (cc < H) ? p1[(size_t)gr * H + cc] : 0.f;
                    float b = (cc < H) ? p2[(size_t)gr * H + cc] : 0.f;
                    s[q] = a + b; d[q] = a - b;
                }
            }
            #pragma unroll
            for (int j = 0; j < 11; ++j) {
                float w = GW[j];
                v4 sv = {s[j], s[j+1], s[j+2], s[j+3]};
                v4 dv = {d[j], d[j+1], d[j+2], d[j+3]};
                v4 ws_ = w * sv, wd = w * dv;
                hs += ws_; hd += wd; hss += ws_ * sv; hdd += wd * dv;
            }
        }
        h4* row = &hb[r * PITCH + cg_ * 4];
        row[0] = (h4){(_Float16)hs.x, (_Float16)hd.x, (_Float16)hss.x, (_Float16)hdd.x};
        row[1] = (h4){(_Float16)hs.y, (_Float16)hd.y, (_Float16)hss.y, (_Float16)hdd.y};
        row[2] = (h4){(_Float16)hs.z, (_Float16)hd.z, (_Float16)hss.z, (_Float16)hdd.z};
        row[3] = (h4){(_Float16)hs.w, (_Float16)hd.w, (_Float16)hss.w, (_Float16)hdd.w};
    }
    __syncthreads();

    // ---- vertical pass + ssim/cs: thread = 1 column x OPT rows (rolling)
    const int col  = tid & 31;
    const int row0 = (tid >> 5) * OPT;
    const float colm = (tx0 + col < outHW) ? 1.f : 0.f;
    v4 A[OPT];
    #pragma unroll
    for (int k = 0; k < OPT; ++k) A[k] = 0.f;

    #pragma unroll
    for (int r = 0; r < OPT + 10; ++r) {
        h4 h = hb[(row0 + r) * PITCH + col];
        v4 f = {(float)h.x, (float)h.y, (float)h.z, (float)h.w};
        #pragma unroll
        for (int k = 0; k < OPT; ++k) {
            const int j = r - k;
            if (j >= 0 && j < 11) A[k] += GW[j] * f;
        }
    }

    float ssim_t = 0.f, cs_t = 0.f;
    #pragma unroll
    for (int k = 0; k < OPT; ++k) {
        float mask = colm * ((ty0 + row0 + k < outHW) ? 1.f : 0.f);
        float mu_s = A[k].x, mu_d = A[k].y;
        float P = mu_s * mu_s, Q = mu_d * mu_d;
        float U = A[k].z - P, V = A[k].w - Q;
        float v1 = 0.5f * (U - V) + C2;
        float v2 = 0.5f * (U + V) + C2;
        float n1 = 0.5f * (P - Q) + C1;
        float d1 = 0.5f * (P + Q) + C1;
        float csv = v1 * frcp(v2);
        float ssv = n1 * csv * frcp(d1);
        cs_t   += mask * csv;
        ssim_t += mask * ssv;
    }

    // ---- block reduction + spread atomics
    #pragma unroll
    for (int off = 32; off > 0; off >>= 1) {
        ssim_t += __shfl_down(ssim_t, off);
        cs_t   += __shfl_down(cs_t, off);
    }
    int wave = tid >> 6, lane = tid & 63;
    if (lane == 0) { red[wave] = ssim_t; red[4 + wave] = cs_t; }
    __syncthreads();
    if (tid == 0) {
        float s = red[0] + red[1] + red[2] + red[3];
        float c2s = red[4] + red[5] + red[6] + red[7];
        int slot = (tx0 + ty0 * 5 + nc * 11) & (NSLOT - 1);
        atomicAdd(&acc[slot], s);
        atomicAdd(&acc[NSLOT + slot], c2s);
    }
}

__device__ __forceinline__ void finalize_body(const float* __restrict__ acc,
                                              float* __restrict__ out)
{
    const float w[5] = {0.0448f, 0.2856f, 0.3001f, 0.2363f, 0.1333f};
    float ms[5], mc[5];
    for (int l = 0; l < 5; ++l) {
        float s = 0.f, c = 0.f;
        for (int k = 0; k < NSLOT; ++k) {
            s += acc[2 * NSLOT * l + k];
            c += acc[2 * NSLOT * l + NSLOT + k];
        }
        int oh = (512 >> l) - 10;
        float cnt = 48.f * (float)oh * (float)oh;
        ms[l] = (s / cnt + 1.f) * 0.5f;
        mc[l] = (c / cnt + 1.f) * 0.5f;
    }
    float p2 = powf(ms[4], w[4]);
    float r = 1.f;
    for (int i = 0; i < 4; ++i) r *= powf(mc[i], w[i]) * p2;
    out[0] = r;
}

// workspace float offsets (acc at 0, barrier at 512, buffers from 2048)
#define OFF_L1A 2048
#define OFF_L1B (OFF_L1A + 3145728)
#define OFF_L2A (OFF_L1B + 3145728)
#define OFF_L2B (OFF_L2A + 786432)
#define OFF_L3A (OFF_L2B + 786432)
#define OFF_L3B (OFF_L3A + 196608)
#define OFF_L4A (OFF_L3B + 196608)
#define OFF_L4B (OFF_L4A + 49152)

// ---------------- cooperative mega-kernel ----------------

__global__ __launch_bounds__(256, 4) void ssim_all_kernel(
    const float* __restrict__ img1, const float* __restrict__ img2,
    float* __restrict__ ws, float* __restrict__ out)
{
    __shared__ h4 hb[74 * 33];
    __shared__ float red[8];

    const int tid = threadIdx.x;
    const int bid = blockIdx.x;
    const unsigned nb = gridDim.x;

    float*    acc = ws;
    unsigned* cnt = (unsigned*)(ws + 512);   // 32 lines x 16 u32
    unsigned* gen = (unsigned*)(ws + 1024);
    float* l1a = ws + OFF_L1A; float* l1b = ws + OFF_L1B;
    float* l2a = ws + OFF_L2A; float* l2b = ws + OFF_L2B;
    float* l3a = ws + OFF_L3A; float* l3b = ws + OFF_L3B;
    float* l4a = ws + OFF_L4A; float* l4b = ws + OFF_L4B;

    for (int t = bid; t < 6144; t += nb) {            // L0: H=512 T=64 16x8x48
        int nc = t >> 7, k = t & 127;
        ssim_tile<64>(img1, img2, l1a, l1b, 512, 1, acc,
                      nc, (k & 15) * 32, (k >> 4) * 64, hb, red, tid);
    }
    grid_bar(cnt, gen, nb, 1, tid, bid);

    for (int t = bid; t < 1536; t += nb) {            // L1: H=256 T=64 8x4x48
        int nc = t >> 5, k = t & 31;
        ssim_tile<64>(l1a, l1b, l2a, l2b, 256, 1, acc + 64,
                      nc, (k & 7) * 32, (k >> 3) * 64, hb, red, tid);
    }
    grid_bar(cnt, gen, nb, 2, tid, bid);

    for (int t = bid; t < 768; t += nb) {             // L2: H=128 T=32 4x4x48
        int nc = t >> 4, k = t & 15;
        ssim_tile<32>(l2a, l2b, l3a, l3b, 128, 1, acc + 128,
                      nc, (k & 3) * 32, (k >> 2) * 32, hb, red, tid);
    }
    grid_bar(cnt, gen, nb, 3, tid, bid);

    for (int t = bid; t < 384; t += nb) {             // L3: H=64 T=16 2x4x48
        int nc = t >> 3, k = t & 7;
        ssim_tile<16>(l3a, l3b, l4a, l4b, 64, 1, acc + 192,
                      nc, (k & 1) * 32, (k >> 1) * 16, hb, red, tid);
    }
    grid_bar(cnt, gen, nb, 4, tid, bid);

    for (int t = bid; t < 96; t += nb) {              // L4: H=32 T=16 1x2x48
        int nc = t >> 1, k = t & 1;
        ssim_tile<16>(l4a, l4b, nullptr, nullptr, 32, 0, acc + 256,
                      nc, 0, k * 16, hb, red, tid);
    }
    grid_bar(cnt, gen, nb, 5, tid, bid);

    if (bid == 0 && tid == 0) finalize_body(acc, out);
}

// ---------------- fallback multi-dispatch path ----------------

template<int TROWS>
__global__ __launch_bounds__(256, 4) void ssim_level_kernel(
    const float* __restrict__ img1, const float* __restrict__ img2,
    float* __restrict__ ds1, float* __restrict__ ds2,
    int H, int do_ds, float* __restrict__ acc)
{
    __shared__ h4 hb[(TROWS + 10) * 33];
    __shared__ float red[8];
    ssim_tile<TROWS>(img1, img2, ds1, ds2, H, do_ds, acc,
                     blockIdx.z, blockIdx.x * 32, blockIdx.y * TROWS,
                     hb, red, threadIdx.x);
}

__global__ void finalize_kernel(const float* __restrict__ acc, float* __restrict__ out)
{
    if (threadIdx.x == 0 && blockIdx.x == 0) finalize_body(acc, out);
}

extern "C" void kernel_launch(void* const* d_in, const int* in_sizes, int n_in,
                              void* d_out, int out_size, void* d_ws, size_t ws_size,
                              hipStream_t stream)
{
    const float* img1 = (const float*)d_in[0];
    const float* img2 = (const float*)d_in[1];
    float* out = (float*)d_out;
    float* ws  = (float*)d_ws;

    // zero acc (floats 0..320) + barrier state (floats 512..1025)
    hipMemsetAsync(ws, 0, 8192, stream);

    // ---- try the cooperative mega-kernel, sized by the runtime's capacity
    int bpc = 0;
    hipError_t qerr = hipOccupancyMaxActiveBlocksPerMultiprocessor(
        &bpc, ssim_all_kernel, 256, 0);
    bool ok = false;
    if (qerr == hipSuccess && bpc > 0) {
        if (bpc > 8) bpc = 8;
        int nblocks = bpc * 256;                 // 256 CUs on MI355X
        if (nblocks > 6144) nblocks = 6144;
        void* args[] = {(void*)&img1, (void*)&img2, (void*)&ws, (void*)&out};
        hipError_t lerr = hipLaunchCooperativeKernel(
            ssim_all_kernel, dim3(nblocks), dim3(256), args, 0, stream);
        ok = (lerr == hipSuccess);
    }
    if (ok) return;

    // ---- fallback: multi-dispatch (always correct)
    float* acc = ws;
    float* l1a = ws + OFF_L1A; float* l1b = ws + OFF_L1B;
    float* l2a = ws + OFF_L2A; float* l2b = ws + OFF_L2B;
    float* l3a = ws + OFF_L3A; float* l3b = ws + OFF_L3B;
    float* l4a = ws + OFF_L4A; float* l4b = ws + OFF_L4B;

    ssim_level_kernel<64><<<dim3(16, 8, 48), 256, 0, stream>>>(
        img1, img2, l1a, l1b, 512, 1, acc);
    ssim_level_kernel<64><<<dim3(8, 4, 48), 256, 0, stream>>>(
        l1a, l1b, l2a, l2b, 256, 1, acc + 64);
    ssim_level_kernel<32><<<dim3(4, 4, 48), 256, 0, stream>>>(
        l2a, l2b, l3a, l3b, 128, 1, acc + 128);
    ssim_level_kernel<16><<<dim3(2, 4, 48), 256, 0, stream>>>(
        l3a, l3b, l4a, l4b, 64, 1, acc + 192);
    ssim_level_kernel<16><<<dim3(1, 2, 48), 256, 0, stream>>>(
        l4a, l4b, nullptr, nullptr, 32, 0, acc + 256);

    finalize_kernel<<<1, 64, 0, stream>>>(acc, out);
}

// Round 10
// 308.341 us; speedup vs baseline: 1.7766x; 1.1022x over previous
//
#include <hip/hip_runtime.h>

// MS-SSIM, 5 levels, 16x3x512x512 fp32, scalar fp32 out.
//
// R10: cooperative mega-kernel, barrier made cheap.
// R9 analysis: ~40us/barrier residual = per-block agent-scope fences
// (release -> buffer_wbl2 = whole-XCD L2 writeback, x2048 blocks) + all
// waiters polling ONE gen word. Fixes:
//  - ds (next-level) buffers written via agent-scope write-through atomic
//    stores -> no dirty L2 for inter-phase data -> release has ~nothing
//    to flush; release folded into the arrival RMW (RELEASE/AGENT).
//  - gen replicated over 32 cache lines; block0 publishes all copies;
//    each waiter polls its own line (64 pollers/line, not 2047/line).
//  - acquire = one directed agent fence per block after wake (buffer_inv,
//    needed for cross-XCD reads).
//  - last barrier replaced by last-man-out finalize (ACQ_REL arrival
//    counter; the closing block computes the weighted product).
// Kernel internals = verified ssim_tile (s/d reduction, fp16 LDS tiles,
// rolling v-pass, fused 2x2 avg-pool). Fallback multi-dispatch kept.

#define NSLOT 32

typedef float v4  __attribute__((ext_vector_type(4)));
typedef float v2f __attribute__((ext_vector_type(2)));
typedef _Float16 h4 __attribute__((ext_vector_type(4)));

__device__ __forceinline__ float frcp(float x) { return __builtin_amdgcn_rcpf(x); }

__device__ __forceinline__ void store_agent(float* p, float v) {
    __hip_atomic_store(p, v, __ATOMIC_RELAXED, __HIP_MEMORY_SCOPE_AGENT);
}

// ---- grid barrier: spread arrivals, replicated gen, directed fences
__device__ __forceinline__ void grid_bar(unsigned* cnt, unsigned* gen,
                                         unsigned nb, unsigned round,
                                         int tid, int bid)
{
    __syncthreads();
    if (tid == 0) {
        // arrival with release ordering (ds data is write-through -> cheap)
        __hip_atomic_fetch_add(&cnt[(bid & 31) * 16], 1u,
                               __ATOMIC_RELEASE, __HIP_MEMORY_SCOPE_AGENT);
        if (bid == 0) {
            const unsigned target = nb * round;
            for (;;) {
                unsigned s = 0;
                #pragma unroll
                for (int i = 0; i < 32; ++i)
                    s += __hip_atomic_load(&cnt[i * 16], __ATOMIC_RELAXED,
                                           __HIP_MEMORY_SCOPE_AGENT);
                if (s >= target) break;
                __builtin_amdgcn_s_sleep(2);
            }
            #pragma unroll
            for (int i = 0; i < 32; ++i)
                __hip_atomic_store(&gen[i * 16], round, __ATOMIC_RELAXED,
                                   __HIP_MEMORY_SCOPE_AGENT);
        } else {
            unsigned* mygen = &gen[(bid & 31) * 16];
            while (__hip_atomic_load(mygen, __ATOMIC_RELAXED,
                                     __HIP_MEMORY_SCOPE_AGENT) < round)
                __builtin_amdgcn_s_sleep(2);
        }
        // acquire: drop stale lines before reading other XCDs' data
        __builtin_amdgcn_fence(__ATOMIC_ACQUIRE, "agent");
    }
    __syncthreads();
}

template<int TROWS>
__device__ __forceinline__ void ssim_tile(
    const float* __restrict__ img1, const float* __restrict__ img2,
    float* __restrict__ ds1, float* __restrict__ ds2,
    int H, int do_ds, float* __restrict__ acc,
    int nc, int tx0, int ty0, h4* hb, float* red, int tid)
{
    constexpr int HR    = TROWS + 10;        // h-rows per tile
    constexpr int OPT   = TROWS * 32 / 256;  // output rows per thread
    constexpr int PITCH = 33;                // pixels per LDS row (32+1 pad)

    const float GW[11] = {0.00102840f, 0.00759877f, 0.03600070f, 0.10936069f,
                          0.21300636f, 0.26601172f, 0.21300636f, 0.10936069f,
                          0.03600070f, 0.00759877f, 0.00102840f};
    const float C1 = 1e-4f, C2 = 9e-4f;

    const int outHW = H - 10;
    const float* p1 = img1 + (size_t)nc * H * H;
    const float* p2 = img2 + (size_t)nc * H * H;

    // ---- fused 2x2 avg-pool of the block's core region (independent work)
    if (do_ds) {
        const int H2 = H >> 1;
        #pragma unroll
        for (int t = tid; t < 16 * (TROWS / 2); t += 256) {
            int r = t >> 4, cdd = t & 15;
            int iy = ty0 + 2 * r, ix = tx0 + 2 * cdd;
            if (iy + 1 < H) {
                v2f a0 = *(const v2f*)(p1 + (size_t)iy * H + ix);
                v2f a1 = *(const v2f*)(p1 + (size_t)(iy + 1) * H + ix);
                v2f b0 = *(const v2f*)(p2 + (size_t)iy * H + ix);
                v2f b1 = *(const v2f*)(p2 + (size_t)(iy + 1) * H + ix);
                size_t o = (size_t)nc * H2 * H2
                         + (size_t)((ty0 >> 1) + r) * H2 + ((tx0 >> 1) + cdd);
                store_agent(&ds1[o], 0.25f * ((a0.x + a0.y) + (a1.x + a1.y)));
                store_agent(&ds2[o], 0.25f * ((b0.x + b0.y) + (b1.x + b1.y)));
            }
        }
    }

    // ---- horizontal pass: HR rows x 8 col-groups (4 cols each)
    for (int task = tid; task < HR * 8; task += 256) {
        const int r  = task >> 3, cg_ = task & 7;
        const int gr = ty0 + r;
        const int c0 = tx0 + cg_ * 4;
        v4 hs = 0.f, hd = 0.f, hss = 0.f, hdd = 0.f;
        if (gr < H) {
            float s[16], d[16];
            if (c0 + 16 <= H) {
                const float* pa = p1 + (size_t)gr * H + c0;
                const float* pb = p2 + (size_t)gr * H + c0;
                #pragma unroll
                for (int q = 0; q < 4; ++q) {
                    v4 va = *(const v4*)(pa + 4 * q);
                    v4 vb = *(const v4*)(pb + 4 * q);
                    v4 sv = va + vb, dv = va - vb;
                    s[4*q+0] = sv.x; s[4*q+1] = sv.y; s[4*q+2] = sv.z; s[4*q+3] = sv.w;
                    d[4*q+0] = dv.x; d[4*q+1] = dv.y; d[4*q+2] = dv.z; d[4*q+3] = dv.w;
                }
            } else {
                #pragma unroll
                for (int q = 0; q < 16; ++q) {
                    int cc = c0 + q;
                    float a = (cc < H) ? p1[(size_t)gr * H + cc] : 0.f;
                    float b = (cc < H) ? p2[(size_t)gr * H + cc] : 0.f;
                    s[q] = a + b; d[q] = a - b;
                }
            }
            #pragma unroll
            for (int j = 0; j < 11; ++j) {
                float w = GW[j];
                v4 sv = {s[j], s[j+1], s[j+2], s[j+3]};
                v4 dv = {d[j], d[j+1], d[j+2], d[j+3]};
                v4 ws_ = w * sv, wd = w * dv;
                hs += ws_; hd += wd; hss += ws_ * sv; hdd += wd * dv;
            }
        }
        h4* row = &hb[r * PITCH + cg_ * 4];
        row[0] = (h4){(_Float16)hs.x, (_Float16)hd.x, (_Float16)hss.x, (_Float16)hdd.x};
        row[1] = (h4){(_Float16)hs.y, (_Float16)hd.y, (_Float16)hss.y, (_Float16)hdd.y};
        row[2] = (h4){(_Float16)hs.z, (_Float16)hd.z, (_Float16)hss.z, (_Float16)hdd.z};
        row[3] = (h4){(_Float16)hs.w, (_Float16)hd.w, (_Float16)hss.w, (_Float16)hdd.w};
    }
    __syncthreads();

    // ---- vertical pass + ssim/cs: thread = 1 column x OPT rows (rolling)
    const int col  = tid & 31;
    const int row0 = (tid >> 5) * OPT;
    const float colm = (tx0 + col < outHW) ? 1.f : 0.f;
    v4 A[OPT];
    #pragma unroll
    for (int k = 0; k < OPT; ++k) A[k] = 0.f;

    #pragma unroll
    for (int r = 0; r < OPT + 10; ++r) {
        h4 h = hb[(row0 + r) * PITCH + col];
        v4 f = {(float)h.x, (float)h.y, (float)h.z, (float)h.w};
        #pragma unroll
        for (int k = 0; k < OPT; ++k) {
            const int j = r - k;
            if (j >= 0 && j < 11) A[k] += GW[j] * f;
        }
    }

    float ssim_t = 0.f, cs_t = 0.f;
    #pragma unroll
    for (int k = 0; k < OPT; ++k) {
        float mask = colm * ((ty0 + row0 + k < outHW) ? 1.f : 0.f);
        float mu_s = A[k].x, mu_d = A[k].y;
        float P = mu_s * mu_s, Q = mu_d * mu_d;
        float U = A[k].z - P, V = A[k].w - Q;
        float v1 = 0.5f * (U - V) + C2;
        float v2 = 0.5f * (U + V) + C2;
        float n1 = 0.5f * (P - Q) + C1;
        float d1 = 0.5f * (P + Q) + C1;
        float csv = v1 * frcp(v2);
        float ssv = n1 * csv * frcp(d1);
        cs_t   += mask * csv;
        ssim_t += mask * ssv;
    }

    // ---- block reduction + spread atomics
    #pragma unroll
    for (int off = 32; off > 0; off >>= 1) {
        ssim_t += __shfl_down(ssim_t, off);
        cs_t   += __shfl_down(cs_t, off);
    }
    int wave = tid >> 6, lane = tid & 63;
    if (lane == 0) { red[wave] = ssim_t; red[4 + wave] = cs_t; }
    __syncthreads();
    if (tid == 0) {
        float s = red[0] + red[1] + red[2] + red[3];
        float c2s = red[4] + red[5] + red[6] + red[7];
        int slot = (tx0 + ty0 * 5 + nc * 11) & (NSLOT - 1);
        atomicAdd(&acc[slot], s);
        atomicAdd(&acc[NSLOT + slot], c2s);
    }
}

__device__ __forceinline__ void finalize_body(const float* __restrict__ acc,
                                              float* __restrict__ out)
{
    const float w[5] = {0.0448f, 0.2856f, 0.3001f, 0.2363f, 0.1333f};
    float ms[5], mc[5];
    for (int l = 0; l < 5; ++l) {
        float s = 0.f, c = 0.f;
        for (int k = 0; k < NSLOT; ++k) {
            s += acc[2 * NSLOT * l + k];
            c += acc[2 * NSLOT * l + NSLOT + k];
        }
        int oh = (512 >> l) - 10;
        float cnt = 48.f * (float)oh * (float)oh;
        ms[l] = (s / cnt + 1.f) * 0.5f;
        mc[l] = (c / cnt + 1.f) * 0.5f;
    }
    float p2 = powf(ms[4], w[4]);
    float r = 1.f;
    for (int i = 0; i < 4; ++i) r *= powf(mc[i], w[i]) * p2;
    out[0] = r;
}

// workspace float offsets (acc at 0, barrier state 512..1535, buffers 2048+)
#define OFF_L1A 2048
#define OFF_L1B (OFF_L1A + 3145728)
#define OFF_L2A (OFF_L1B + 3145728)
#define OFF_L2B (OFF_L2A + 786432)
#define OFF_L3A (OFF_L2B + 786432)
#define OFF_L3B (OFF_L3A + 196608)
#define OFF_L4A (OFF_L3B + 196608)
#define OFF_L4B (OFF_L4A + 49152)

// ---------------- cooperative mega-kernel ----------------

__global__ __launch_bounds__(256, 4) void ssim_all_kernel(
    const float* __restrict__ img1, const float* __restrict__ img2,
    float* __restrict__ ws, float* __restrict__ out)
{
    __shared__ h4 hb[74 * 33];
    __shared__ float red[8];

    const int tid = threadIdx.x;
    const int bid = blockIdx.x;
    const unsigned nb = gridDim.x;

    float*    acc = ws;
    unsigned* cnt = (unsigned*)(ws + 512);    // 32 lines x 16 u32
    unsigned* gen = (unsigned*)(ws + 1024);   // 32 lines x 16 u32
    unsigned* fin = (unsigned*)(ws + 1536);   // last-man-out counter
    float* l1a = ws + OFF_L1A; float* l1b = ws + OFF_L1B;
    float* l2a = ws + OFF_L2A; float* l2b = ws + OFF_L2B;
    float* l3a = ws + OFF_L3A; float* l3b = ws + OFF_L3B;
    float* l4a = ws + OFF_L4A; float* l4b = ws + OFF_L4B;

    for (int t = bid; t < 6144; t += nb) {            // L0: H=512 T=64 16x8x48
        int nc = t >> 7, k = t & 127;
        ssim_tile<64>(img1, img2, l1a, l1b, 512, 1, acc,
                      nc, (k & 15) * 32, (k >> 4) * 64, hb, red, tid);
    }
    grid_bar(cnt, gen, nb, 1, tid, bid);

    for (int t = bid; t < 1536; t += nb) {            // L1: H=256 T=64 8x4x48
        int nc = t >> 5, k = t & 31;
        ssim_tile<64>(l1a, l1b, l2a, l2b, 256, 1, acc + 64,
                      nc, (k & 7) * 32, (k >> 3) * 64, hb, red, tid);
    }
    grid_bar(cnt, gen, nb, 2, tid, bid);

    for (int t = bid; t < 768; t += nb) {             // L2: H=128 T=32 4x4x48
        int nc = t >> 4, k = t & 15;
        ssim_tile<32>(l2a, l2b, l3a, l3b, 128, 1, acc + 128,
                      nc, (k & 3) * 32, (k >> 2) * 32, hb, red, tid);
    }
    grid_bar(cnt, gen, nb, 3, tid, bid);

    for (int t = bid; t < 384; t += nb) {             // L3: H=64 T=16 2x4x48
        int nc = t >> 3, k = t & 7;
        ssim_tile<16>(l3a, l3b, l4a, l4b, 64, 1, acc + 192,
                      nc, (k & 1) * 32, (k >> 1) * 16, hb, red, tid);
    }
    grid_bar(cnt, gen, nb, 4, tid, bid);

    for (int t = bid; t < 96; t += nb) {              // L4: H=32 T=16 1x2x48
        int nc = t >> 1, k = t & 1;
        ssim_tile<16>(l4a, l4b, nullptr, nullptr, 32, 0, acc + 256,
                      nc, 0, k * 16, hb, red, tid);
    }

    // ---- last-man-out finalize (no wake round)
    __syncthreads();
    if (tid == 0) {
        unsigned old = __hip_atomic_fetch_add(fin, 1u, __ATOMIC_ACQ_REL,
                                              __HIP_MEMORY_SCOPE_AGENT);
        if (old == nb - 1) {
            __builtin_amdgcn_fence(__ATOMIC_ACQUIRE, "agent");
            finalize_body(acc, out);
        }
    }
}

// ---------------- fallback multi-dispatch path ----------------

template<int TROWS>
__global__ __launch_bounds__(256, 4) void ssim_level_kernel(
    const float* __restrict__ img1, const float* __restrict__ img2,
    float* __restrict__ ds1, float* __restrict__ ds2,
    int H, int do_ds, float* __restrict__ acc)
{
    __shared__ h4 hb[(TROWS + 10) * 33];
    __shared__ float red[8];
    ssim_tile<TROWS>(img1, img2, ds1, ds2, H, do_ds, acc,
                     blockIdx.z, blockIdx.x * 32, blockIdx.y * TROWS,
                     hb, red, threadIdx.x);
}

__global__ void finalize_kernel(const float* __restrict__ acc, float* __restrict__ out)
{
    if (threadIdx.x == 0 && blockIdx.x == 0) finalize_body(acc, out);
}

extern "C" void kernel_launch(void* const* d_in, const int* in_sizes, int n_in,
                              void* d_out, int out_size, void* d_ws, size_t ws_size,
                              hipStream_t stream)
{
    const float* img1 = (const float*)d_in[0];
    const float* img2 = (const float*)d_in[1];
    float* out = (float*)d_out;
    float* ws  = (float*)d_ws;

    // zero acc (floats 0..320) + barrier state (floats 512..1552)
    hipMemsetAsync(ws, 0, 8192, stream);

    // ---- try the cooperative mega-kernel, sized by the runtime's capacity
    int bpc = 0;
    hipError_t qerr = hipOccupancyMaxActiveBlocksPerMultiprocessor(
        &bpc, ssim_all_kernel, 256, 0);
    bool ok = false;
    if (qerr == hipSuccess && bpc > 0) {
        if (bpc > 8) bpc = 8;
        int nblocks = bpc * 256;                 // 256 CUs on MI355X
        if (nblocks > 6144) nblocks = 6144;
        void* args[] = {(void*)&img1, (void*)&img2, (void*)&ws, (void*)&out};
        hipError_t lerr = hipLaunchCooperativeKernel(
            ssim_all_kernel, dim3(nblocks), dim3(256), args, 0, stream);
        ok = (lerr == hipSuccess);
    }
    if (ok) return;

    // ---- fallback: multi-dispatch (always correct)
    float* acc = ws;
    float* l1a = ws + OFF_L1A; float* l1b = ws + OFF_L1B;
    float* l2a = ws + OFF_L2A; float* l2b = ws + OFF_L2B;
    float* l3a = ws + OFF_L3A; float* l3b = ws + OFF_L3B;
    float* l4a = ws + OFF_L4A; float* l4b = ws + OFF_L4B;

    ssim_level_kernel<64><<<dim3(16, 8, 48), 256, 0, stream>>>(
        img1, img2, l1a, l1b, 512, 1, acc);
    ssim_level_kernel<64><<<dim3(8, 4, 48), 256, 0, stream>>>(
        l1a, l1b, l2a, l2b, 256, 1, acc + 64);
    ssim_level_kernel<32><<<dim3(4, 4, 48), 256, 0, stream>>>(
        l2a, l2b, l3a, l3b, 128, 1, acc + 128);
    ssim_level_kernel<16><<<dim3(2, 4, 48), 256, 0, stream>>>(
        l3a, l3b, l4a, l4b, 64, 1, acc + 192);
    ssim_level_kernel<16><<<dim3(1, 2, 48), 256, 0, stream>>>(
        l4a, l4b, nullptr, nullptr, 32, 0, acc + 256);

    finalize_kernel<<<1, 64, 0, stream>>>(acc, out);
}